// Round 8
// baseline (165.371 us; speedup 1.0000x reference)
//
#include <hip/hip_runtime.h>
#include <hip/hip_bf16.h>
#include <math.h>

// MultiSimilarityLoss on MI355X.
// x: [n,128] fp32 L2-normalized; t: [n] int32 labels; out: 4 fp32
// (loss, prec, mean_pos_sim(last row), mean_neg_sim(last row)).
// ep = EPOCH_NUM/300 = 1.0, BASE=0.5, POS_MARGIN=0.9, NEG_MARGIN=0.1.
//
// R8: persistent neg kernel (768 blocks = 3/CU, tile-stride over 2080
// triangular tiles) with register prefetch: half-1 globals load during
// half-0 MFMA; next tile's half-0 loads during the (long) epilogue.
// Finalize parallelized to 32 blocks with atomicAdd into out (prep zeroes
// d_out). Reg budget at (256,3) cap=170: acc 64 + prefetch 32 + frags 32
// + addr ~30 -> no spill (R6 showed spilling at cap=128).
// exp args expanded: neg 50(s-.5)+(.1-s)^2 = s^2+49.8s-24.99
//                    pos -2(s-.5)+(s-.9)^2 = s^2-3.8s+1.81

#define D 128
#define NL 128   // labels are 0..99; padded

typedef __attribute__((ext_vector_type(8))) short short8;
typedef __attribute__((ext_vector_type(4))) float float4v;

// ---------------- wave reduce helpers ----------------
__device__ inline float waveSum(float v) {
    #pragma unroll
    for (int o = 32; o > 0; o >>= 1) v += __shfl_down(v, o, 64);
    return v;
}
__device__ inline float waveMin(float v) {
    #pragma unroll
    for (int o = 32; o > 0; o >>= 1) v = fminf(v, __shfl_down(v, o, 64));
    return v;
}

// ---------------- kernel A: convert + bucket + zero workspace ---------------
__global__ __launch_bounds__(256) void prep_kernel(
    const float* __restrict__ x, ushort* __restrict__ xb, int total8,
    const int* __restrict__ t, int* __restrict__ offs, int* __restrict__ list,
    float* __restrict__ part, float* __restrict__ last4,
    float* __restrict__ out, int n, int nconv)
{
    const int tid = threadIdx.x;
    const int bx = blockIdx.x;
    if (bx < nconv) {
        const int g = bx * 256 + tid;
        if (g >= total8) return;
        const float4* src = (const float4*)(x) + g * 2;
        float4 a = src[0], b = src[1];
        float f[8] = {a.x, a.y, a.z, a.w, b.x, b.y, b.z, b.w};
        ushort r[8];
        #pragma unroll
        for (int i = 0; i < 8; ++i) {
            unsigned u = __float_as_uint(f[i]);
            r[i] = (ushort)((u + 0x7FFFu + ((u >> 16) & 1u)) >> 16);   // RNE
        }
        uint4 packed;
        packed.x = (unsigned)r[0] | ((unsigned)r[1] << 16);
        packed.y = (unsigned)r[2] | ((unsigned)r[3] << 16);
        packed.z = (unsigned)r[4] | ((unsigned)r[5] << 16);
        packed.w = (unsigned)r[6] | ((unsigned)r[7] << 16);
        ((uint4*)xb)[g] = packed;
        return;
    }
    if (bx > nconv) {   // zero part
        const int zb = bx - nconv - 1;
        const int g4 = zb * 1024 + tid * 4;
        if (g4 < 8 * n)
            *(float4*)(part + g4) = (float4){0.f, 0.f, 0.f, 0.f};
        return;
    }
    // bucketing block (also zeroes last4 and out accumulators)
    __shared__ int cnt[NL], cur[NL];
    if (tid < 4) { last4[tid] = 0.f; out[tid] = 0.f; }
    if (tid < NL) cnt[tid] = 0;
    __syncthreads();
    for (int j = tid; j < n; j += 256) atomicAdd(&cnt[t[j]], 1);
    __syncthreads();
    if (tid == 0) {
        int acc = 0;
        for (int g = 0; g < NL; ++g) { cur[g] = acc; offs[g] = acc; acc += cnt[g]; }
        offs[NL] = acc;
    }
    __syncthreads();
    for (int j = tid; j < n; j += 256) {
        int p = atomicAdd(&cur[t[j]], 1);
        list[p] = j;
    }
}

// ---------------- kernel B: per-row positive stats, label-group LDS --------
__global__ __launch_bounds__(256) void pos_kernel3(
    const float* __restrict__ x, const ushort* __restrict__ xb,
    const int* __restrict__ offs, const int* __restrict__ list,
    float* __restrict__ pos_min, float* __restrict__ pos_sum,
    float* __restrict__ last4, int n)
{
    const int g = blockIdx.x, sub = blockIdx.y;
    const int s0 = offs[g], m = offs[g + 1] - s0;
    if (m <= 0) return;
    const int chunk = (m + 7) >> 3;
    const int rb = sub * chunk, re = min(m, rb + chunk);
    if (rb >= re) return;    // uniform per block, before any barrier

    __shared__ __align__(16) uint4 cb[128 * 16];    // 32 KB col chunk (swizzled)
    __shared__ __align__(16) float xi[4][D];        // own rows (fp32)

    const int tid = threadIdx.x;
    const int wid = tid >> 6, lane = tid & 63;
    const bool multi = (m > 128);

    if (!multi) {   // stage all group cols once
        for (int idx = tid; idx < m * 16; idx += 256) {
            int cl = idx >> 4, q = idx & 15;
            cb[cl * 16 + (q ^ (cl & 15))] =
                ((const uint4*)xb)[(size_t)list[s0 + cl] * 16 + q];
        }
        __syncthreads();
    }

    for (int r0 = rb; r0 < re; r0 += 4) {
        const int r = r0 + wid;
        const bool active = (r < re);
        const int i = active ? list[s0 + r] : 0;
        if (active && lane < 32)
            ((float4*)xi[wid])[lane] = ((const float4*)(x + (size_t)i * D))[lane];

        float mn = INFINITY, ps = 0.f, ss = 0.f, sc = 0.f;
        for (int c0 = 0; c0 < m; c0 += 128) {
            const int cc = min(128, m - c0);
            if (multi) {
                __syncthreads();
                for (int idx = tid; idx < cc * 16; idx += 256) {
                    int cl = idx >> 4, q = idx & 15;
                    cb[cl * 16 + (q ^ (cl & 15))] =
                        ((const uint4*)xb)[(size_t)list[s0 + c0 + cl] * 16 + q];
                }
                __syncthreads();
            }
            if (active) {
                const float* xu = xi[wid];
                for (int cl = lane; cl < cc; cl += 64) {
                    float d = 0.f;
                    #pragma unroll
                    for (int q = 0; q < 16; ++q) {
                        uint4 v = cb[cl * 16 + (q ^ (cl & 15))];
                        const float* u = xu + q * 8;
                        d += __uint_as_float(v.x << 16)         * u[0];
                        d += __uint_as_float(v.x & 0xffff0000u) * u[1];
                        d += __uint_as_float(v.y << 16)         * u[2];
                        d += __uint_as_float(v.y & 0xffff0000u) * u[3];
                        d += __uint_as_float(v.z << 16)         * u[4];
                        d += __uint_as_float(v.z & 0xffff0000u) * u[5];
                        d += __uint_as_float(v.w << 16)         * u[6];
                        d += __uint_as_float(v.w & 0xffff0000u) * u[7];
                    }
                    if (d < 0.9f) {            // excludes j==i (sim ~ 1.0)
                        mn = fminf(mn, d);
                        ps += __expf(fmaf(d, d, fmaf(-3.8f, d, 1.81f)));
                        ss += d; sc += 1.f;
                    }
                }
            }
        }
        mn = waveMin(mn); ps = waveSum(ps); ss = waveSum(ss); sc = waveSum(sc);
        if (active && lane == 0) {
            pos_min[i] = mn;
            pos_sum[i] = ps;
            if (i == n - 1) { last4[0] = ss; last4[1] = sc; }
        }
    }
}

// ---------------- kernel C: persistent triangular MFMA + neg epilogue ------
__global__ __launch_bounds__(256, 3) void neg_kernel_tri(
    const ushort* __restrict__ xb, const int* __restrict__ t,
    const float* __restrict__ pos_min,
    float* __restrict__ part, float* __restrict__ last4, int n, int ntri)
{
    __shared__ __align__(16) ushort ABbuf[2 * 128 * 64];   // 32 KB (A half | B half)
    __shared__ int   labr[128], labc[128];
    __shared__ float pths[128], pthc[128];

    const int tid = threadIdx.x;
    const int w = tid >> 6, lane = tid & 63;
    const int wy = w >> 1, wx = w & 1;
    const int quad = lane >> 4, lq = lane & 15;
    const int stride = gridDim.x;

    uint4* Au = (uint4*)ABbuf;              // [128][8] chunks, swizzled
    uint4* Bu = Au + 128 * 8;
    const uint4* xbv = (const uint4*)xb;
    const short8* As = (const short8*)Au;
    const short8* Bs = (const short8*)Bu;
    float* pp_r = (float*)ABbuf;            // [32][129] row partials
    float* pp_c = ((float*)ABbuf) + 32 * 129;  // [8][129] col partials

    const int prow = tid >> 3, pq = tid & 7;   // staging coords (rows prow+32*it)

    int b = blockIdx.x;
    if (b >= ntri) return;
    // decode tile b -> (r,c), r >= c
    int r = (int)((sqrtf(8.0f * (float)b + 1.0f) - 1.0f) * 0.5f);
    while ((r + 1) * (r + 2) / 2 <= b) ++r;
    while (r * (r + 1) / 2 > b) --r;
    int c = b - r * (r + 1) / 2;
    int i0 = r * 128, j0 = c * 128;

    uint4 pa[4], pb[4];
    #pragma unroll
    for (int it = 0; it < 4; ++it) {        // prefetch h0 of first tile
        const int row = prow + it * 32;
        pa[it] = xbv[(size_t)(i0 + row) * 16 + pq];
        pb[it] = xbv[(size_t)(j0 + row) * 16 + pq];
    }

    while (true) {
        const bool offdiag = (r != c);
        const bool has_last = (i0 == n - 128);

        __syncthreads();                    // prev tile's LDS use complete
        for (int l = tid; l < 128; l += 256) {
            labr[l] = t[i0 + l];
            labc[l] = t[j0 + l];
            pths[l] = fmaxf(0.1f, pos_min[i0 + l] - 0.5f);
            pthc[l] = fmaxf(0.1f, pos_min[j0 + l] - 0.5f);
        }
        #pragma unroll
        for (int it = 0; it < 4; ++it) {    // stage h0 from regs
            const int row = prow + it * 32;
            const int qs = pq ^ (row & 7);
            Au[row * 8 + qs] = pa[it];
            Bu[row * 8 + qs] = pb[it];
        }
        #pragma unroll
        for (int it = 0; it < 4; ++it) {    // prefetch h1 (in flight over MFMA h0)
            const int row = prow + it * 32;
            pa[it] = xbv[(size_t)(i0 + row) * 16 + 8 + pq];
            pb[it] = xbv[(size_t)(j0 + row) * 16 + 8 + pq];
        }

        float4v acc[4][4];
        #pragma unroll
        for (int a = 0; a < 4; ++a)
            #pragma unroll
            for (int d2 = 0; d2 < 4; ++d2) acc[a][d2] = (float4v){0.f, 0.f, 0.f, 0.f};

        __syncthreads();
        #pragma unroll
        for (int s = 0; s < 2; ++s) {       // MFMA half 0
            short8 af[4], bf[4];
            #pragma unroll
            for (int tt = 0; tt < 4; ++tt) {
                const int ra = wy * 64 + tt * 16 + lq;
                const int rb2 = wx * 64 + tt * 16 + lq;
                const int swz = (s * 4 + quad) ^ (lq & 7);
                af[tt] = As[ra * 8 + swz];
                bf[tt] = Bs[rb2 * 8 + swz];
            }
            #pragma unroll
            for (int tr = 0; tr < 4; ++tr)
                #pragma unroll
                for (int tc = 0; tc < 4; ++tc)
                    acc[tr][tc] = __builtin_amdgcn_mfma_f32_16x16x32_bf16(
                        af[tr], bf[tc], acc[tr][tc], 0, 0, 0);
        }
        __syncthreads();                    // done reading h0 LDS
        #pragma unroll
        for (int it = 0; it < 4; ++it) {    // stage h1 from regs
            const int row = prow + it * 32;
            const int qs = pq ^ (row & 7);
            Au[row * 8 + qs] = pa[it];
            Bu[row * 8 + qs] = pb[it];
        }
        // decode next tile, prefetch its h0 (hidden under MFMA h1 + epilogue)
        const int bn = b + stride;
        int rn = r, cn = c;
        if (bn < ntri) {
            rn = r;
            while ((rn + 1) * (rn + 2) / 2 <= bn) ++rn;
            cn = bn - rn * (rn + 1) / 2;
            const int i0n = rn * 128, j0n = cn * 128;
            #pragma unroll
            for (int it = 0; it < 4; ++it) {
                const int row = prow + it * 32;
                pa[it] = xbv[(size_t)(i0n + row) * 16 + pq];
                pb[it] = xbv[(size_t)(j0n + row) * 16 + pq];
            }
        }
        __syncthreads();
        #pragma unroll
        for (int s = 0; s < 2; ++s) {       // MFMA half 1
            short8 af[4], bf[4];
            #pragma unroll
            for (int tt = 0; tt < 4; ++tt) {
                const int ra = wy * 64 + tt * 16 + lq;
                const int rb2 = wx * 64 + tt * 16 + lq;
                const int swz = (s * 4 + quad) ^ (lq & 7);
                af[tt] = As[ra * 8 + swz];
                bf[tt] = Bs[rb2 * 8 + swz];
            }
            #pragma unroll
            for (int tr = 0; tr < 4; ++tr)
                #pragma unroll
                for (int tc = 0; tc < 4; ++tc)
                    acc[tr][tc] = __builtin_amdgcn_mfma_f32_16x16x32_bf16(
                        af[tr], bf[tc], acc[tr][tc], 0, 0, 0);
        }
        __syncthreads();                    // done reading LDS; alias pp

        int lcv[4]; float pcv[4];
        #pragma unroll
        for (int tc = 0; tc < 4; ++tc) {
            const int cl = wx * 64 + tc * 16 + lq;
            lcv[tc] = labc[cl];
            pcv[tc] = pthc[cl];
        }
        float colp[4] = {0.f, 0.f, 0.f, 0.f};

        #pragma unroll
        for (int tr = 0; tr < 4; ++tr) {
            #pragma unroll
            for (int reg = 0; reg < 4; ++reg) {
                const int row_loc = wy * 64 + tr * 16 + quad * 4 + reg;
                const float pthr = pths[row_loc];
                const int lr = labr[row_loc];
                float ns = 0.f;
                #pragma unroll
                for (int tc = 0; tc < 4; ++tc) {
                    const float s = acc[tr][tc][reg];
                    const bool diff = (lr != lcv[tc]);
                    const float e = __expf(fmaf(s, s, fmaf(49.8f, s, -24.99f)));
                    ns       += (diff & (s > pthr))    ? e : 0.f;
                    colp[tc] += (diff & (s > pcv[tc])) ? e : 0.f;
                }
                pp_r[(wx * 16 + lq) * 129 + row_loc] = ns;

                if (has_last && (i0 + row_loc == n - 1)) {   // exact last-row stats
                    float ssim = 0.f, ncf = 0.f;
                    #pragma unroll
                    for (int tc = 0; tc < 4; ++tc) {
                        const float s = acc[tr][tc][reg];
                        if ((lr != lcv[tc]) & (s > pthr)) { ssim += s; ncf += 1.f; }
                    }
                    #pragma unroll
                    for (int o = 1; o < 16; o <<= 1) {
                        ssim += __shfl_xor(ssim, o, 64);
                        ncf  += __shfl_xor(ncf, o, 64);
                    }
                    if (lq == 0 && ncf > 0.f) {
                        atomicAdd(&last4[2], ssim);
                        atomicAdd(&last4[3], ncf);
                    }
                }
            }
        }
        if (offdiag) {
            #pragma unroll
            for (int tc = 0; tc < 4; ++tc)
                pp_c[(wy * 4 + quad) * 129 + (wx * 64 + tc * 16 + lq)] = colp[tc];
        }
        __syncthreads();

        if (tid < 128) {
            float s = 0.f;
            #pragma unroll
            for (int cc = 0; cc < 32; ++cc) s += pp_r[cc * 129 + tid];
            atomicAdd(&part[(size_t)(c & 7) * n + i0 + tid], s);   // <=8 writers/slice
            if (offdiag) {
                float s2 = 0.f;
                #pragma unroll
                for (int cc = 0; cc < 8; ++cc) s2 += pp_c[cc * 129 + tid];
                atomicAdd(&part[(size_t)(r & 7) * n + j0 + tid], s2);
            }
        }

        if (bn >= ntri) break;
        b = bn; r = rn; c = cn; i0 = rn * 128; j0 = cn * 128;
    }
}

// ---------------- kernel D: finalize (32 blocks, atomic into out) ----------
__global__ __launch_bounds__(256) void finalize_kernel(
    const float* __restrict__ pos_sum, const float* __restrict__ part,
    const float* __restrict__ last4, float* __restrict__ out, int n)
{
    const int tid = threadIdx.x;
    const int i = blockIdx.x * 256 + tid;
    float s = 0.f;
    #pragma unroll
    for (int sl = 0; sl < 8; ++sl) s += part[(size_t)sl * n + i];
    float l = 0.f, nno = 0.f;
    if (s > 0.f)       // has_neg <=> any exp term (each >= e^-20 > 0)
        l = 0.5f * log1pf(pos_sum[i]) + 0.02f * log1pf(s);
    else
        nno = 1.f;
    __shared__ float rb[2][4];
    const int lane = tid & 63, wv = tid >> 6;
    l = waveSum(l); nno = waveSum(nno);
    if (lane == 0) { rb[0][wv] = l; rb[1][wv] = nno; }
    __syncthreads();
    if (tid == 0) {
        float L = rb[0][0] + rb[0][1] + rb[0][2] + rb[0][3];
        float P = rb[1][0] + rb[1][1] + rb[1][2] + rb[1][3];
        atomicAdd(&out[0], L / (float)n);
        atomicAdd(&out[1], P / (float)n);
        if (blockIdx.x == 0) {
            out[2] = last4[0] / fmaxf(last4[1], 1.f);
            out[3] = last4[2] / fmaxf(last4[3], 1.f);
        }
    }
}

// ---------------- launch ----------------
extern "C" void kernel_launch(void* const* d_in, const int* in_sizes, int n_in,
                              void* d_out, int out_size, void* d_ws, size_t ws_size,
                              hipStream_t stream) {
    const float* x = (const float*)d_in[0];
    const int*   t = (const int*)d_in[1];
    const int n = in_sizes[1];   // 8192

    float* ws      = (float*)d_ws;
    float* pos_min = ws;                       // [n]
    float* pos_sum = ws + n;                   // [n]
    float* last4   = ws + 2 * n;               // [4]   (zeroed by prep)
    float* part    = ws + 2 * n + 4;           // [8*n] (zeroed by prep)
    int*   offs    = (int*)(ws + 10 * n + 4);             // [NL+1]
    int*   list    = (int*)(ws + 10 * n + 4 + NL + 1);    // [n]
    size_t xb_off  = ((size_t)(11 * n + 4 + NL + 1) + 3) & ~(size_t)3;
    ushort* xb     = (ushort*)(ws + xb_off);              // [n*128] bf16, 16B aligned

    const int total8 = n * D / 8;
    const int nconv = (total8 + 255) / 256;
    const int nzero = (8 * n + 1023) / 1024;
    prep_kernel<<<nconv + 1 + nzero, 256, 0, stream>>>(
        x, xb, total8, t, offs, list, part, last4, (float*)d_out, n, nconv);

    pos_kernel3<<<dim3(NL, 8), 256, 0, stream>>>(x, xb, offs, list,
                                                 pos_min, pos_sum, last4, n);

    const int nb = n / 128;                    // 64
    const int ntri = nb * (nb + 1) / 2;        // 2080
    neg_kernel_tri<<<768, 256, 0, stream>>>(xb, t, pos_min, part, last4, n, ntri);

    finalize_kernel<<<n / 256, 256, 0, stream>>>(pos_sum, part, last4,
                                                 (float*)d_out, n);
}

// Round 9
// 130.741 us; speedup vs baseline: 1.2649x; 1.2649x over previous
//
#include <hip/hip_runtime.h>
#include <hip/hip_bf16.h>
#include <math.h>

// MultiSimilarityLoss on MI355X.
// x: [n,128] fp32 L2-normalized; t: [n] int32 labels; out: 4 fp32
// (loss, prec, mean_pos_sim(last row), mean_neg_sim(last row)).
// ep = EPOCH_NUM/300 = 1.0, BASE=0.5, POS_MARGIN=0.9, NEG_MARGIN=0.1.
//
// R9: revert neg kernel to R7 (R8's persistent+register-prefetch spilled:
// VGPR 84 + 125 MB scratch WRITE — no headroom for prefetch regs at
// (256,3) cap ~170). Keep R8's parallel finalize + prep zeroing d_out.
// exp args expanded: neg 50(s-.5)+(.1-s)^2 = s^2+49.8s-24.99
//                    pos -2(s-.5)+(s-.9)^2 = s^2-3.8s+1.81

#define D 128
#define NL 128   // labels are 0..99; padded

typedef __attribute__((ext_vector_type(8))) short short8;
typedef __attribute__((ext_vector_type(4))) float float4v;

// ---------------- wave reduce helpers ----------------
__device__ inline float waveSum(float v) {
    #pragma unroll
    for (int o = 32; o > 0; o >>= 1) v += __shfl_down(v, o, 64);
    return v;
}
__device__ inline float waveMin(float v) {
    #pragma unroll
    for (int o = 32; o > 0; o >>= 1) v = fminf(v, __shfl_down(v, o, 64));
    return v;
}

// ---------------- kernel A: convert + bucket + zero workspace ---------------
__global__ __launch_bounds__(256) void prep_kernel(
    const float* __restrict__ x, ushort* __restrict__ xb, int total8,
    const int* __restrict__ t, int* __restrict__ offs, int* __restrict__ list,
    float* __restrict__ part, float* __restrict__ last4,
    float* __restrict__ out, int n, int nconv)
{
    const int tid = threadIdx.x;
    const int bx = blockIdx.x;
    if (bx < nconv) {
        const int g = bx * 256 + tid;
        if (g >= total8) return;
        const float4* src = (const float4*)(x) + g * 2;
        float4 a = src[0], b = src[1];
        float f[8] = {a.x, a.y, a.z, a.w, b.x, b.y, b.z, b.w};
        ushort r[8];
        #pragma unroll
        for (int i = 0; i < 8; ++i) {
            unsigned u = __float_as_uint(f[i]);
            r[i] = (ushort)((u + 0x7FFFu + ((u >> 16) & 1u)) >> 16);   // RNE
        }
        uint4 packed;
        packed.x = (unsigned)r[0] | ((unsigned)r[1] << 16);
        packed.y = (unsigned)r[2] | ((unsigned)r[3] << 16);
        packed.z = (unsigned)r[4] | ((unsigned)r[5] << 16);
        packed.w = (unsigned)r[6] | ((unsigned)r[7] << 16);
        ((uint4*)xb)[g] = packed;
        return;
    }
    if (bx > nconv) {   // zero part
        const int zb = bx - nconv - 1;
        const int g4 = zb * 1024 + tid * 4;
        if (g4 < 8 * n)
            *(float4*)(part + g4) = (float4){0.f, 0.f, 0.f, 0.f};
        return;
    }
    // bucketing block (also zeroes last4 and out accumulators)
    __shared__ int cnt[NL], cur[NL];
    if (tid < 4) { last4[tid] = 0.f; out[tid] = 0.f; }
    if (tid < NL) cnt[tid] = 0;
    __syncthreads();
    for (int j = tid; j < n; j += 256) atomicAdd(&cnt[t[j]], 1);
    __syncthreads();
    if (tid == 0) {
        int acc = 0;
        for (int g = 0; g < NL; ++g) { cur[g] = acc; offs[g] = acc; acc += cnt[g]; }
        offs[NL] = acc;
    }
    __syncthreads();
    for (int j = tid; j < n; j += 256) {
        int p = atomicAdd(&cur[t[j]], 1);
        list[p] = j;
    }
}

// ---------------- kernel B: per-row positive stats, label-group LDS --------
__global__ __launch_bounds__(256) void pos_kernel3(
    const float* __restrict__ x, const ushort* __restrict__ xb,
    const int* __restrict__ offs, const int* __restrict__ list,
    float* __restrict__ pos_min, float* __restrict__ pos_sum,
    float* __restrict__ last4, int n)
{
    const int g = blockIdx.x, sub = blockIdx.y;
    const int s0 = offs[g], m = offs[g + 1] - s0;
    if (m <= 0) return;
    const int chunk = (m + 7) >> 3;
    const int rb = sub * chunk, re = min(m, rb + chunk);
    if (rb >= re) return;    // uniform per block, before any barrier

    __shared__ __align__(16) uint4 cb[128 * 16];    // 32 KB col chunk (swizzled)
    __shared__ __align__(16) float xi[4][D];        // own rows (fp32)

    const int tid = threadIdx.x;
    const int wid = tid >> 6, lane = tid & 63;
    const bool multi = (m > 128);

    if (!multi) {   // stage all group cols once
        for (int idx = tid; idx < m * 16; idx += 256) {
            int cl = idx >> 4, q = idx & 15;
            cb[cl * 16 + (q ^ (cl & 15))] =
                ((const uint4*)xb)[(size_t)list[s0 + cl] * 16 + q];
        }
        __syncthreads();
    }

    for (int r0 = rb; r0 < re; r0 += 4) {
        const int r = r0 + wid;
        const bool active = (r < re);
        const int i = active ? list[s0 + r] : 0;
        if (active && lane < 32)
            ((float4*)xi[wid])[lane] = ((const float4*)(x + (size_t)i * D))[lane];

        float mn = INFINITY, ps = 0.f, ss = 0.f, sc = 0.f;
        for (int c0 = 0; c0 < m; c0 += 128) {
            const int cc = min(128, m - c0);
            if (multi) {
                __syncthreads();
                for (int idx = tid; idx < cc * 16; idx += 256) {
                    int cl = idx >> 4, q = idx & 15;
                    cb[cl * 16 + (q ^ (cl & 15))] =
                        ((const uint4*)xb)[(size_t)list[s0 + c0 + cl] * 16 + q];
                }
                __syncthreads();
            }
            if (active) {
                const float* xu = xi[wid];
                for (int cl = lane; cl < cc; cl += 64) {
                    float d = 0.f;
                    #pragma unroll
                    for (int q = 0; q < 16; ++q) {
                        uint4 v = cb[cl * 16 + (q ^ (cl & 15))];
                        const float* u = xu + q * 8;
                        d += __uint_as_float(v.x << 16)         * u[0];
                        d += __uint_as_float(v.x & 0xffff0000u) * u[1];
                        d += __uint_as_float(v.y << 16)         * u[2];
                        d += __uint_as_float(v.y & 0xffff0000u) * u[3];
                        d += __uint_as_float(v.z << 16)         * u[4];
                        d += __uint_as_float(v.z & 0xffff0000u) * u[5];
                        d += __uint_as_float(v.w << 16)         * u[6];
                        d += __uint_as_float(v.w & 0xffff0000u) * u[7];
                    }
                    if (d < 0.9f) {            // excludes j==i (sim ~ 1.0)
                        mn = fminf(mn, d);
                        ps += __expf(fmaf(d, d, fmaf(-3.8f, d, 1.81f)));
                        ss += d; sc += 1.f;
                    }
                }
            }
        }
        mn = waveMin(mn); ps = waveSum(ps); ss = waveSum(ss); sc = waveSum(sc);
        if (active && lane == 0) {
            pos_min[i] = mn;
            pos_sum[i] = ps;
            if (i == n - 1) { last4[0] = ss; last4[1] = sc; }
        }
    }
}

// ---------------- kernel C: triangular MFMA sim + negative epilogue --------
// K split into two 64-wide halves -> LDS ~35 KB. launch_bounds(256,3):
// reg cap ~170 >= ~145 needed -> no spill, 3 blocks/CU. (R7 version —
// do NOT add prefetch registers; R8 proved they cause scratch spills.)
__global__ __launch_bounds__(256, 3) void neg_kernel_tri(
    const ushort* __restrict__ xb, const int* __restrict__ t,
    const float* __restrict__ pos_min,
    float* __restrict__ part, float* __restrict__ last4, int n)
{
    __shared__ __align__(16) ushort ABbuf[2 * 128 * 64];   // 32 KB (A half | B half)
    __shared__ int   labr[128], labc[128];
    __shared__ float pths[128], pthc[128];

    // triangular decode: block b -> (r, c), r >= c
    int b = blockIdx.x;
    int r = (int)((sqrtf(8.0f * (float)b + 1.0f) - 1.0f) * 0.5f);
    while ((r + 1) * (r + 2) / 2 <= b) ++r;
    while (r * (r + 1) / 2 > b) --r;
    const int c = b - r * (r + 1) / 2;
    const bool offdiag = (r != c);

    const int tid = threadIdx.x;
    const int w = tid >> 6, lane = tid & 63;
    const int wy = w >> 1, wx = w & 1;
    const int quad = lane >> 4, lq = lane & 15;
    const int i0 = r * 128, j0 = c * 128;
    const bool has_last = (i0 == n - 128);

    for (int l = tid; l < 128; l += 256) {
        labr[l] = t[i0 + l];
        labc[l] = t[j0 + l];
        pths[l] = fmaxf(0.1f, pos_min[i0 + l] - 0.5f);   // combined threshold
        pthc[l] = fmaxf(0.1f, pos_min[j0 + l] - 0.5f);
    }

    uint4* Au = (uint4*)ABbuf;              // [128][8] chunks, swizzled
    uint4* Bu = (uint4*)(ABbuf + 128 * 64);
    const uint4* xbv = (const uint4*)xb;
    const short8* As = (const short8*)Au;
    const short8* Bs = (const short8*)Bu;

    float4v acc[4][4];
    #pragma unroll
    for (int a = 0; a < 4; ++a)
        #pragma unroll
        for (int d2 = 0; d2 < 4; ++d2) acc[a][d2] = (float4v){0.f, 0.f, 0.f, 0.f};

    #pragma unroll
    for (int h = 0; h < 2; ++h) {           // K half: cols [h*64, h*64+64)
        if (h) __syncthreads();             // done reading previous half
        #pragma unroll
        for (int it = 0; it < 4; ++it) {
            int gidx = tid + it * 256;      // 0..1023
            int row = gidx >> 3, q = gidx & 7;
            int qs = q ^ (row & 7);
            Au[row * 8 + qs] = xbv[(size_t)(i0 + row) * 16 + h * 8 + q];
            Bu[row * 8 + qs] = xbv[(size_t)(j0 + row) * 16 + h * 8 + q];
        }
        __syncthreads();
        #pragma unroll
        for (int s = 0; s < 2; ++s) {       // k = h*64 + s*32 + quad*8 + j
            short8 af[4], bf[4];
            #pragma unroll
            for (int tt = 0; tt < 4; ++tt) {
                const int ra = wy * 64 + tt * 16 + lq;
                const int rb2 = wx * 64 + tt * 16 + lq;
                af[tt] = As[ra * 8 + ((s * 4 + quad) ^ (lq & 7))];
                bf[tt] = Bs[rb2 * 8 + ((s * 4 + quad) ^ (lq & 7))];
            }
            #pragma unroll
            for (int tr = 0; tr < 4; ++tr)
                #pragma unroll
                for (int tc = 0; tc < 4; ++tc)
                    acc[tr][tc] = __builtin_amdgcn_mfma_f32_16x16x32_bf16(
                        af[tr], bf[tc], acc[tr][tc], 0, 0, 0);
        }
    }
    __syncthreads();     // all waves done reading A/B before aliasing

    float* pp_r = (float*)ABbuf;            // [32][129] row partials (16.5 KB)
    float* pp_c = ((float*)ABbuf) + 32 * 129;  // [8][129] col partials (4.1 KB)

    int lcv[4]; float pcv[4];
    #pragma unroll
    for (int tc = 0; tc < 4; ++tc) {
        const int cl = wx * 64 + tc * 16 + lq;
        lcv[tc] = labc[cl];
        pcv[tc] = pthc[cl];
    }
    float colp[4] = {0.f, 0.f, 0.f, 0.f};

    #pragma unroll
    for (int tr = 0; tr < 4; ++tr) {
        #pragma unroll
        for (int reg = 0; reg < 4; ++reg) {
            const int row_loc = wy * 64 + tr * 16 + quad * 4 + reg;
            const float pthr = pths[row_loc];
            const int lr = labr[row_loc];
            float ns = 0.f;
            #pragma unroll
            for (int tc = 0; tc < 4; ++tc) {
                const float s = acc[tr][tc][reg];
                const bool diff = (lr != lcv[tc]);
                const float e = __expf(fmaf(s, s, fmaf(49.8f, s, -24.99f)));
                ns       += (diff & (s > pthr))    ? e : 0.f;
                colp[tc] += (diff & (s > pcv[tc])) ? e : 0.f;
            }
            pp_r[(wx * 16 + lq) * 129 + row_loc] = ns;

            if (has_last && (i0 + row_loc == n - 1)) {   // exact last-row stats
                float ssim = 0.f, ncf = 0.f;
                #pragma unroll
                for (int tc = 0; tc < 4; ++tc) {
                    const float s = acc[tr][tc][reg];
                    if ((lr != lcv[tc]) & (s > pthr)) { ssim += s; ncf += 1.f; }
                }
                #pragma unroll
                for (int o = 1; o < 16; o <<= 1) {
                    ssim += __shfl_xor(ssim, o, 64);
                    ncf  += __shfl_xor(ncf, o, 64);
                }
                if (lq == 0 && ncf > 0.f) {
                    atomicAdd(&last4[2], ssim);
                    atomicAdd(&last4[3], ncf);
                }
            }
        }
    }
    if (offdiag) {
        #pragma unroll
        for (int tc = 0; tc < 4; ++tc)
            pp_c[(wy * 4 + quad) * 129 + (wx * 64 + tc * 16 + lq)] = colp[tc];
    }
    __syncthreads();

    if (tid < 128) {
        float s = 0.f;
        #pragma unroll
        for (int cc = 0; cc < 32; ++cc) s += pp_r[cc * 129 + tid];
        atomicAdd(&part[(size_t)(c & 7) * n + i0 + tid], s);   // <=8 writers/slice
        if (offdiag) {
            float s2 = 0.f;
            #pragma unroll
            for (int cc = 0; cc < 8; ++cc) s2 += pp_c[cc * 129 + tid];
            atomicAdd(&part[(size_t)(r & 7) * n + j0 + tid], s2);
        }
    }
}

// ---------------- kernel D: finalize (32 blocks, atomic into out) ----------
__global__ __launch_bounds__(256) void finalize_kernel(
    const float* __restrict__ pos_sum, const float* __restrict__ part,
    const float* __restrict__ last4, float* __restrict__ out, int n)
{
    const int tid = threadIdx.x;
    const int i = blockIdx.x * 256 + tid;
    float s = 0.f;
    #pragma unroll
    for (int sl = 0; sl < 8; ++sl) s += part[(size_t)sl * n + i];
    float l = 0.f, nno = 0.f;
    if (s > 0.f)       // has_neg <=> any exp term (each >= e^-20 > 0)
        l = 0.5f * log1pf(pos_sum[i]) + 0.02f * log1pf(s);
    else
        nno = 1.f;
    __shared__ float rb[2][4];
    const int lane = tid & 63, wv = tid >> 6;
    l = waveSum(l); nno = waveSum(nno);
    if (lane == 0) { rb[0][wv] = l; rb[1][wv] = nno; }
    __syncthreads();
    if (tid == 0) {
        float L = rb[0][0] + rb[0][1] + rb[0][2] + rb[0][3];
        float P = rb[1][0] + rb[1][1] + rb[1][2] + rb[1][3];
        atomicAdd(&out[0], L / (float)n);
        atomicAdd(&out[1], P / (float)n);
        if (blockIdx.x == 0) {
            out[2] = last4[0] / fmaxf(last4[1], 1.f);
            out[3] = last4[2] / fmaxf(last4[3], 1.f);
        }
    }
}

// ---------------- launch ----------------
extern "C" void kernel_launch(void* const* d_in, const int* in_sizes, int n_in,
                              void* d_out, int out_size, void* d_ws, size_t ws_size,
                              hipStream_t stream) {
    const float* x = (const float*)d_in[0];
    const int*   t = (const int*)d_in[1];
    const int n = in_sizes[1];   // 8192

    float* ws      = (float*)d_ws;
    float* pos_min = ws;                       // [n]
    float* pos_sum = ws + n;                   // [n]
    float* last4   = ws + 2 * n;               // [4]   (zeroed by prep)
    float* part    = ws + 2 * n + 4;           // [8*n] (zeroed by prep)
    int*   offs    = (int*)(ws + 10 * n + 4);             // [NL+1]
    int*   list    = (int*)(ws + 10 * n + 4 + NL + 1);    // [n]
    size_t xb_off  = ((size_t)(11 * n + 4 + NL + 1) + 3) & ~(size_t)3;
    ushort* xb     = (ushort*)(ws + xb_off);              // [n*128] bf16, 16B aligned

    const int total8 = n * D / 8;
    const int nconv = (total8 + 255) / 256;
    const int nzero = (8 * n + 1023) / 1024;
    prep_kernel<<<nconv + 1 + nzero, 256, 0, stream>>>(
        x, xb, total8, t, offs, list, part, last4, (float*)d_out, n, nconv);

    pos_kernel3<<<dim3(NL, 8), 256, 0, stream>>>(x, xb, offs, list,
                                                 pos_min, pos_sum, last4, n);

    const int nb = n / 128;                    // 64
    const int ntri = nb * (nb + 1) / 2;        // 2080
    neg_kernel_tri<<<ntri, 256, 0, stream>>>(xb, t, pos_min, part, last4, n);

    finalize_kernel<<<n / 256, 256, 0, stream>>>(pos_sum, part, last4,
                                                 (float*)d_out, n);
}

// Round 10
// 125.500 us; speedup vs baseline: 1.3177x; 1.0418x over previous
//
#include <hip/hip_runtime.h>
#include <hip/hip_bf16.h>
#include <math.h>

// MultiSimilarityLoss on MI355X.
// x: [n,128] fp32 L2-normalized; t: [n] int32 labels; out: 4 fp32
// (loss, prec, mean_pos_sim(last row), mean_neg_sim(last row)).
// ep = EPOCH_NUM/300 = 1.0, BASE=0.5, POS_MARGIN=0.9, NEG_MARGIN=0.1.
//
// R10: pos+neg FUSED into one grid. neg tiles use fixed pth=0.1 (no
// pos_min dependency); rows where pos_min > 0.6 (pth would exceed 0.1,
// incl. empty-pos rows with pos_min=+inf) are exactly recomputed in
// finalize (block-cooperative row scan; statistically 0 rows on random
// data, but correct for any data). Row/col predicates become identical
// -> lighter epilogue, fewer live regs (anti-spill margin at (256,3)).
// exp args expanded: neg 50(s-.5)+(.1-s)^2 = s^2+49.8s-24.99
//                    pos -2(s-.5)+(s-.9)^2 = s^2-3.8s+1.81

#define D 128
#define NL 128   // labels are 0..99; padded

typedef __attribute__((ext_vector_type(8))) short short8;
typedef __attribute__((ext_vector_type(4))) float float4v;

// ---------------- wave reduce helpers ----------------
__device__ inline float waveSum(float v) {
    #pragma unroll
    for (int o = 32; o > 0; o >>= 1) v += __shfl_down(v, o, 64);
    return v;
}
__device__ inline float waveMin(float v) {
    #pragma unroll
    for (int o = 32; o > 0; o >>= 1) v = fminf(v, __shfl_down(v, o, 64));
    return v;
}

// ---------------- kernel A: convert + bucket + zero workspace ---------------
__global__ __launch_bounds__(256) void prep_kernel(
    const float* __restrict__ x, ushort* __restrict__ xb, int total8,
    const int* __restrict__ t, int* __restrict__ offs, int* __restrict__ list,
    float* __restrict__ part, float* __restrict__ last4,
    float* __restrict__ out, int n, int nconv)
{
    const int tid = threadIdx.x;
    const int bx = blockIdx.x;
    if (bx < nconv) {
        const int g = bx * 256 + tid;
        if (g >= total8) return;
        const float4* src = (const float4*)(x) + g * 2;
        float4 a = src[0], b = src[1];
        float f[8] = {a.x, a.y, a.z, a.w, b.x, b.y, b.z, b.w};
        ushort r[8];
        #pragma unroll
        for (int i = 0; i < 8; ++i) {
            unsigned u = __float_as_uint(f[i]);
            r[i] = (ushort)((u + 0x7FFFu + ((u >> 16) & 1u)) >> 16);   // RNE
        }
        uint4 packed;
        packed.x = (unsigned)r[0] | ((unsigned)r[1] << 16);
        packed.y = (unsigned)r[2] | ((unsigned)r[3] << 16);
        packed.z = (unsigned)r[4] | ((unsigned)r[5] << 16);
        packed.w = (unsigned)r[6] | ((unsigned)r[7] << 16);
        ((uint4*)xb)[g] = packed;
        return;
    }
    if (bx > nconv) {   // zero part
        const int zb = bx - nconv - 1;
        const int g4 = zb * 1024 + tid * 4;
        if (g4 < 8 * n)
            *(float4*)(part + g4) = (float4){0.f, 0.f, 0.f, 0.f};
        return;
    }
    // bucketing block (also zeroes last4 and out accumulators)
    __shared__ int cnt[NL], cur[NL];
    if (tid < 4) { last4[tid] = 0.f; out[tid] = 0.f; }
    if (tid < NL) cnt[tid] = 0;
    __syncthreads();
    for (int j = tid; j < n; j += 256) atomicAdd(&cnt[t[j]], 1);
    __syncthreads();
    if (tid == 0) {
        int acc = 0;
        for (int g = 0; g < NL; ++g) { cur[g] = acc; offs[g] = acc; acc += cnt[g]; }
        offs[NL] = acc;
    }
    __syncthreads();
    for (int j = tid; j < n; j += 256) {
        int p = atomicAdd(&cur[t[j]], 1);
        list[p] = j;
    }
}

// ---------------- kernel B: FUSED pos stats + triangular MFMA neg ----------
// blocks [0,ntri): neg tiles (pth=0.1 fixed). blocks [ntri,ntri+NL*8): pos.
__global__ __launch_bounds__(256, 3) void fused_kernel(
    const float* __restrict__ x, const ushort* __restrict__ xb,
    const int* __restrict__ t,
    const int* __restrict__ offs, const int* __restrict__ list,
    float* __restrict__ pos_min, float* __restrict__ pos_sum,
    float* __restrict__ part, float* __restrict__ last4, int n, int ntri)
{
    __shared__ __align__(16) unsigned char smem[32768 + 2048];
    const int tid = threadIdx.x;
    const int bx = blockIdx.x;

    if (bx < ntri) {
        // ================= NEG tile path =================
        int b = bx;
        int r = (int)((sqrtf(8.0f * (float)b + 1.0f) - 1.0f) * 0.5f);
        while ((r + 1) * (r + 2) / 2 <= b) ++r;
        while (r * (r + 1) / 2 > b) --r;
        const int c = b - r * (r + 1) / 2;
        const bool offdiag = (r != c);

        const int w = tid >> 6, lane = tid & 63;
        const int wy = w >> 1, wx = w & 1;
        const int quad = lane >> 4, lq = lane & 15;
        const int i0 = r * 128, j0 = c * 128;
        const bool has_last = (i0 == n - 128);

        int* labr = (int*)(smem + 32768);
        int* labc = labr + 128;
        for (int l = tid; l < 128; l += 256) {
            labr[l] = t[i0 + l];
            labc[l] = t[j0 + l];
        }

        uint4* Au = (uint4*)smem;               // [128][8] chunks, swizzled
        uint4* Bu = Au + 128 * 8;
        const uint4* xbv = (const uint4*)xb;
        const short8* As = (const short8*)Au;
        const short8* Bs = (const short8*)Bu;

        float4v acc[4][4];
        #pragma unroll
        for (int a = 0; a < 4; ++a)
            #pragma unroll
            for (int d2 = 0; d2 < 4; ++d2) acc[a][d2] = (float4v){0.f, 0.f, 0.f, 0.f};

        #pragma unroll
        for (int h = 0; h < 2; ++h) {           // K half: cols [h*64, h*64+64)
            if (h) __syncthreads();             // done reading previous half
            #pragma unroll
            for (int it = 0; it < 4; ++it) {
                int gidx = tid + it * 256;      // 0..1023
                int row = gidx >> 3, q = gidx & 7;
                int qs = q ^ (row & 7);
                Au[row * 8 + qs] = xbv[(size_t)(i0 + row) * 16 + h * 8 + q];
                Bu[row * 8 + qs] = xbv[(size_t)(j0 + row) * 16 + h * 8 + q];
            }
            __syncthreads();
            #pragma unroll
            for (int s = 0; s < 2; ++s) {       // k = h*64 + s*32 + quad*8 + j
                short8 af[4], bf[4];
                #pragma unroll
                for (int tt = 0; tt < 4; ++tt) {
                    const int ra = wy * 64 + tt * 16 + lq;
                    const int rb2 = wx * 64 + tt * 16 + lq;
                    af[tt] = As[ra * 8 + ((s * 4 + quad) ^ (lq & 7))];
                    bf[tt] = Bs[rb2 * 8 + ((s * 4 + quad) ^ (lq & 7))];
                }
                #pragma unroll
                for (int tr = 0; tr < 4; ++tr)
                    #pragma unroll
                    for (int tc = 0; tc < 4; ++tc)
                        acc[tr][tc] = __builtin_amdgcn_mfma_f32_16x16x32_bf16(
                            af[tr], bf[tc], acc[tr][tc], 0, 0, 0);
            }
        }
        __syncthreads();     // all waves done reading A/B before aliasing

        float* pp_r = (float*)smem;             // [32][129] row partials
        float* pp_c = ((float*)smem) + 32 * 129;   // [8][129] col partials

        int lcv[4];
        #pragma unroll
        for (int tc = 0; tc < 4; ++tc) lcv[tc] = labc[wx * 64 + tc * 16 + lq];
        float colp[4] = {0.f, 0.f, 0.f, 0.f};

        #pragma unroll
        for (int tr = 0; tr < 4; ++tr) {
            #pragma unroll
            for (int reg = 0; reg < 4; ++reg) {
                const int row_loc = wy * 64 + tr * 16 + quad * 4 + reg;
                const int lr = labr[row_loc];
                float ns = 0.f;
                #pragma unroll
                for (int tc = 0; tc < 4; ++tc) {
                    const float s = acc[tr][tc][reg];
                    const bool sel = (lr != lcv[tc]) & (s > 0.1f);
                    const float e = sel
                        ? __expf(fmaf(s, s, fmaf(49.8f, s, -24.99f))) : 0.f;
                    ns += e; colp[tc] += e;
                }
                pp_r[(wx * 16 + lq) * 129 + row_loc] = ns;

                if (has_last && (i0 + row_loc == n - 1)) {  // last-row stats (pth=0.1)
                    float ssim = 0.f, ncf = 0.f;
                    #pragma unroll
                    for (int tc = 0; tc < 4; ++tc) {
                        const float s = acc[tr][tc][reg];
                        if ((lr != lcv[tc]) & (s > 0.1f)) { ssim += s; ncf += 1.f; }
                    }
                    #pragma unroll
                    for (int o = 1; o < 16; o <<= 1) {
                        ssim += __shfl_xor(ssim, o, 64);
                        ncf  += __shfl_xor(ncf, o, 64);
                    }
                    if (lq == 0 && ncf > 0.f) {
                        atomicAdd(&last4[2], ssim);
                        atomicAdd(&last4[3], ncf);
                    }
                }
            }
        }
        if (offdiag) {
            #pragma unroll
            for (int tc = 0; tc < 4; ++tc)
                pp_c[(wy * 4 + quad) * 129 + (wx * 64 + tc * 16 + lq)] = colp[tc];
        }
        __syncthreads();

        if (tid < 128) {
            float s = 0.f;
            #pragma unroll
            for (int cc = 0; cc < 32; ++cc) s += pp_r[cc * 129 + tid];
            atomicAdd(&part[(size_t)(c & 7) * n + i0 + tid], s);  // <=8 writers/slice
            if (offdiag) {
                float s2 = 0.f;
                #pragma unroll
                for (int cc = 0; cc < 8; ++cc) s2 += pp_c[cc * 129 + tid];
                atomicAdd(&part[(size_t)(r & 7) * n + j0 + tid], s2);
            }
        }
        return;
    }

    // ================= POS group path =================
    const int p = bx - ntri;
    const int g = p >> 3, sub = p & 7;
    const int s0 = offs[g], m = offs[g + 1] - s0;
    if (m <= 0) return;
    const int chunk = (m + 7) >> 3;
    const int rb = sub * chunk, re = min(m, rb + chunk);
    if (rb >= re) return;    // uniform per block, before any barrier

    uint4* cb = (uint4*)smem;                       // [128*16] swizzled cols
    float (*xi)[D] = (float(*)[D])(smem + 32768);   // [4][128] own rows fp32

    const int wid = tid >> 6, lane = tid & 63;
    const bool multi = (m > 128);

    if (!multi) {   // stage all group cols once
        for (int idx = tid; idx < m * 16; idx += 256) {
            int cl = idx >> 4, q = idx & 15;
            cb[cl * 16 + (q ^ (cl & 15))] =
                ((const uint4*)xb)[(size_t)list[s0 + cl] * 16 + q];
        }
        __syncthreads();
    }

    for (int r0 = rb; r0 < re; r0 += 4) {
        const int r = r0 + wid;
        const bool active = (r < re);
        const int i = active ? list[s0 + r] : 0;
        if (active && lane < 32)
            ((float4*)xi[wid])[lane] = ((const float4*)(x + (size_t)i * D))[lane];

        float mn = INFINITY, ps = 0.f, ss = 0.f, sc = 0.f;
        for (int c0 = 0; c0 < m; c0 += 128) {
            const int cc = min(128, m - c0);
            if (multi) {
                __syncthreads();
                for (int idx = tid; idx < cc * 16; idx += 256) {
                    int cl = idx >> 4, q = idx & 15;
                    cb[cl * 16 + (q ^ (cl & 15))] =
                        ((const uint4*)xb)[(size_t)list[s0 + c0 + cl] * 16 + q];
                }
                __syncthreads();
            }
            if (active) {
                const float* xu = xi[wid];
                for (int cl = lane; cl < cc; cl += 64) {
                    float d = 0.f;
                    #pragma unroll
                    for (int q = 0; q < 16; ++q) {
                        uint4 v = cb[cl * 16 + (q ^ (cl & 15))];
                        const float* u = xu + q * 8;
                        d += __uint_as_float(v.x << 16)         * u[0];
                        d += __uint_as_float(v.x & 0xffff0000u) * u[1];
                        d += __uint_as_float(v.y << 16)         * u[2];
                        d += __uint_as_float(v.y & 0xffff0000u) * u[3];
                        d += __uint_as_float(v.z << 16)         * u[4];
                        d += __uint_as_float(v.z & 0xffff0000u) * u[5];
                        d += __uint_as_float(v.w << 16)         * u[6];
                        d += __uint_as_float(v.w & 0xffff0000u) * u[7];
                    }
                    if (d < 0.9f) {            // excludes j==i (sim ~ 1.0)
                        mn = fminf(mn, d);
                        ps += __expf(fmaf(d, d, fmaf(-3.8f, d, 1.81f)));
                        ss += d; sc += 1.f;
                    }
                }
            }
        }
        mn = waveMin(mn); ps = waveSum(ps); ss = waveSum(ss); sc = waveSum(sc);
        if (active && lane == 0) {
            pos_min[i] = mn;                   // mn>0.6 flags finalize recompute
            pos_sum[i] = ps;
            if (i == n - 1) { last4[0] = ss; last4[1] = sc; }
        }
    }
}

// ---------------- kernel C: finalize (32 blocks) + exact-path cleanup ------
__global__ __launch_bounds__(256) void finalize_kernel(
    const ushort* __restrict__ xb, const int* __restrict__ t,
    const float* __restrict__ pos_min, const float* __restrict__ pos_sum,
    const float* __restrict__ part, const float* __restrict__ last4,
    float* __restrict__ out, int n)
{
    const int tid = threadIdx.x;
    const int base = blockIdx.x * 256;
    const int i = base + tid;
    const float pm = pos_min[i];
    const bool flag = (pm > 0.6f);   // pth would exceed 0.1 (incl. pm=+inf)

    __shared__ int fl[256];
    __shared__ int nfl, lastflag;
    __shared__ float corr[256];
    __shared__ float xi2[D];
    __shared__ float red[3][4];
    __shared__ float lastst[2];
    if (tid == 0) { nfl = 0; lastflag = 0; }
    __syncthreads();
    if (flag) { int q = atomicAdd(&nfl, 1); fl[q] = tid; }
    __syncthreads();
    const int m = nfl;

    for (int e = 0; e < m; ++e) {    // rare: exact recompute of flagged rows
        const int lr_ = fl[e];
        const int ri = base + lr_;
        if (tid < D)
            xi2[tid] = __uint_as_float(((unsigned)xb[(size_t)ri * D + tid]) << 16);
        __syncthreads();
        const float pth = fmaxf(0.1f, pos_min[ri] - 0.5f);
        const int lab = t[ri];
        float S = 0.f, ss = 0.f, cnt = 0.f;
        for (int j = tid; j < n; j += 256) {
            if (t[j] == lab) continue;
            float d = 0.f;
            const ushort* xr = xb + (size_t)j * D;
            for (int q = 0; q < D; ++q)
                d += __uint_as_float(((unsigned)xr[q]) << 16) * xi2[q];
            if (d > pth) {
                S += __expf(fmaf(d, d, fmaf(49.8f, d, -24.99f)));
                ss += d; cnt += 1.f;
            }
        }
        const int lane = tid & 63, wv = tid >> 6;
        S = waveSum(S); ss = waveSum(ss); cnt = waveSum(cnt);
        if (lane == 0) { red[0][wv] = S; red[1][wv] = ss; red[2][wv] = cnt; }
        __syncthreads();
        if (tid == 0) {
            corr[lr_] = red[0][0] + red[0][1] + red[0][2] + red[0][3];
            if (ri == n - 1) {
                lastst[0] = red[1][0] + red[1][1] + red[1][2] + red[1][3];
                lastst[1] = red[2][0] + red[2][1] + red[2][2] + red[2][3];
                lastflag = 1;
            }
        }
        __syncthreads();
    }

    float s;
    if (flag) {
        s = corr[tid];
    } else {
        s = 0.f;
        #pragma unroll
        for (int sl = 0; sl < 8; ++sl) s += part[(size_t)sl * n + i];
    }
    float l = 0.f, nno = 0.f;
    if (s > 0.f)       // has_neg <=> any exp term (each > 0 in fp32)
        l = 0.5f * log1pf(pos_sum[i]) + 0.02f * log1pf(s);
    else
        nno = 1.f;
    const int lane = tid & 63, wv = tid >> 6;
    l = waveSum(l); nno = waveSum(nno);
    __syncthreads();                  // red[] reuse safety
    if (lane == 0) { red[0][wv] = l; red[1][wv] = nno; }
    __syncthreads();
    if (tid == 0) {
        float L = red[0][0] + red[0][1] + red[0][2] + red[0][3];
        float P = red[1][0] + red[1][1] + red[1][2] + red[1][3];
        atomicAdd(&out[0], L / (float)n);
        atomicAdd(&out[1], P / (float)n);
    }
    if (i == n - 1) {                 // block owning the last row writes stats
        out[2] = last4[0] / fmaxf(last4[1], 1.f);
        float a = lastflag ? lastst[0] : last4[2];
        float b = lastflag ? lastst[1] : last4[3];
        out[3] = a / fmaxf(b, 1.f);
    }
}

// ---------------- launch ----------------
extern "C" void kernel_launch(void* const* d_in, const int* in_sizes, int n_in,
                              void* d_out, int out_size, void* d_ws, size_t ws_size,
                              hipStream_t stream) {
    const float* x = (const float*)d_in[0];
    const int*   t = (const int*)d_in[1];
    const int n = in_sizes[1];   // 8192

    float* ws      = (float*)d_ws;
    float* pos_min = ws;                       // [n]
    float* pos_sum = ws + n;                   // [n]
    float* last4   = ws + 2 * n;               // [4]   (zeroed by prep)
    float* part    = ws + 2 * n + 4;           // [8*n] (zeroed by prep)
    int*   offs    = (int*)(ws + 10 * n + 4);             // [NL+1]
    int*   list    = (int*)(ws + 10 * n + 4 + NL + 1);    // [n]
    size_t xb_off  = ((size_t)(11 * n + 4 + NL + 1) + 3) & ~(size_t)3;
    ushort* xb     = (ushort*)(ws + xb_off);              // [n*128] bf16, 16B aligned

    const int total8 = n * D / 8;
    const int nconv = (total8 + 255) / 256;
    const int nzero = (8 * n + 1023) / 1024;
    prep_kernel<<<nconv + 1 + nzero, 256, 0, stream>>>(
        x, xb, total8, t, offs, list, part, last4, (float*)d_out, n, nconv);

    const int nb = n / 128;                    // 64
    const int ntri = nb * (nb + 1) / 2;        // 2080
    fused_kernel<<<ntri + NL * 8, 256, 0, stream>>>(
        x, xb, t, offs, list, pos_min, pos_sum, part, last4, n, ntri);

    finalize_kernel<<<n / 256, 256, 0, stream>>>(xb, t, pos_min, pos_sum,
                                                 part, last4, (float*)d_out, n);
}